// Round 3
// baseline (56.824 us; speedup 1.0000x reference)
//
#include <hip/hip_runtime.h>

#define Bq   32
#define Cc   8
#define Oo   32
#define FSz  64
#define F2   4096
#define Pp   72
#define TILE 16
#define NBLKS 256            // F2 / TILE
#define SLOTS 512            // NBLKS * 2 batch-halves
#define NTOT (Bq * F2)       // 131072 elements per channel

typedef _Float16 h2 __attribute__((ext_vector_type(2)));

#if __has_builtin(__builtin_amdgcn_fdot2)
#define DOT2(a, b, c) __builtin_amdgcn_fdot2((a), (b), (c), false)
#else
__device__ __forceinline__ float DOT2(h2 a, h2 b, float c) {
    return c + (float)a.x * (float)b.x + (float)a.y * (float)b.y;
}
#endif

__device__ __forceinline__ h2 bc_h2(unsigned u) { return __builtin_bit_cast(h2, u); }

// Block: 512 threads = (bg:2) x (og:16) x (f:16), grid 256 -> 8 waves/CU.
// Tile = 16 consecutive pixels in one row. Each thread: 2 output channels
// (o = og*2+j), 16 batches (its bg half). Weights: 2*72 f16 in 72 VGPRs,
// loaded once (fits under the 128-VGPR / 2-waves-per-SIMD cap). Patches:
// f16 in double-buffered LDS; next batch's x prefetched into registers
// during compute (one barrier per iteration).
__global__ __launch_bounds__(512, 2) void svconv_kernel(
    const float* __restrict__ x, const float* __restrict__ wgt,
    const float* __restrict__ bias, float* __restrict__ y,
    float* __restrict__ psum, float* __restrict__ psumsq)
{
    __shared__ __align__(16) _Float16 pat[2][2][TILE * Pp];  // [bg][buf][1152]
    const int tid  = threadIdx.x;
    const int f    = tid & 15;
    const int og   = (tid >> 4) & 15;
    const int bg   = tid >> 8;
    const int t255 = tid & 255;
    const int fb   = blockIdx.x * TILE;
    const int col  = fb + f;
    const int h    = fb >> 6;
    const int w0   = fb & 63;

    // ---- per-pixel weights for 2 output channels, packed f16 ----
    h2    w2[2][36];
    float bz[2];
#pragma unroll
    for (int j = 0; j < 2; ++j) {
        const int o = og * 2 + j;
        const float* wp = wgt + (size_t)(o * Pp) * F2 + col;
#pragma unroll
        for (int q = 0; q < 36; ++q) {
            float a = wp[(2 * q) * F2];
            float b = wp[(2 * q + 1) * F2];
            h2 t; t.x = (_Float16)a; t.y = (_Float16)b;
            w2[j][q] = t;
        }
        bz[j] = bias[o * F2 + col];
    }

    // ---- patch-fill slots (batch-invariant): 5 slots per thread ----
    // e = t255 + k*256 covers 0..1151; k=4 exists only for t255<128.
    int xb[5];
#pragma unroll
    for (int k = 0; k < 5; ++k) {
        int e = t255 + k * 256;
        if (e < TILE * Pp) {
            int pix = e / 72, p = e - pix * 72;
            int c   = p / 9,  r = p - c * 9;
            int kh  = r / 3,  kw = r - kh * 3;
            int gh  = h + kh - 1;
            int gw  = w0 + pix + kw - 1;
            xb[k] = ((unsigned)gh < (unsigned)FSz && (unsigned)gw < (unsigned)FSz)
                        ? ((c * FSz + gh) * FSz + gw) : -1;
        } else {
            xb[k] = -2;   // slot does not exist
        }
    }

    float s0 = 0.f, s1 = 0.f, ss0 = 0.f, ss1 = 0.f;
    const int b0 = bg * 16;
    const int xstride = Cc * FSz * FSz;   // 32768

    // ---- prologue: stage batch b0 into buffer 0 ----
    {
        float r0[5];
#pragma unroll
        for (int k = 0; k < 5; ++k)
            r0[k] = (xb[k] >= 0) ? x[b0 * xstride + xb[k]] : 0.f;
#pragma unroll
        for (int k = 0; k < 5; ++k)
            if (xb[k] != -2) pat[bg][0][t255 + k * 256] = (_Float16)r0[k];
    }
    __syncthreads();

    for (int bi = 0; bi < 16; ++bi) {
        const int b   = b0 + bi;
        const int cur = bi & 1;

        // prefetch next batch's x into registers (latency hides under compute)
        float r1[5];
        if (bi < 15) {
#pragma unroll
            for (int k = 0; k < 5; ++k)
                r1[k] = (xb[k] >= 0) ? x[(b + 1) * xstride + xb[k]] : 0.f;
        }

        const uint4* pv = (const uint4*)(&pat[bg][cur][f * Pp]);
        float a0 = bz[0], a1 = bz[1];
        {
            uint4 ua[5];
#pragma unroll
            for (int q = 0; q < 5; ++q) ua[q] = pv[q];
#pragma unroll
            for (int q = 0; q < 5; ++q) {
                a0 = DOT2(w2[0][4 * q + 0], bc_h2(ua[q].x), a0);
                a0 = DOT2(w2[0][4 * q + 1], bc_h2(ua[q].y), a0);
                a0 = DOT2(w2[0][4 * q + 2], bc_h2(ua[q].z), a0);
                a0 = DOT2(w2[0][4 * q + 3], bc_h2(ua[q].w), a0);
                a1 = DOT2(w2[1][4 * q + 0], bc_h2(ua[q].x), a1);
                a1 = DOT2(w2[1][4 * q + 1], bc_h2(ua[q].y), a1);
                a1 = DOT2(w2[1][4 * q + 2], bc_h2(ua[q].z), a1);
                a1 = DOT2(w2[1][4 * q + 3], bc_h2(ua[q].w), a1);
            }
        }
        {
            uint4 ub[4];
#pragma unroll
            for (int q = 0; q < 4; ++q) ub[q] = pv[5 + q];
#pragma unroll
            for (int q = 0; q < 4; ++q) {
                a0 = DOT2(w2[0][20 + 4 * q + 0], bc_h2(ub[q].x), a0);
                a0 = DOT2(w2[0][20 + 4 * q + 1], bc_h2(ub[q].y), a0);
                a0 = DOT2(w2[0][20 + 4 * q + 2], bc_h2(ub[q].z), a0);
                a0 = DOT2(w2[0][20 + 4 * q + 3], bc_h2(ub[q].w), a0);
                a1 = DOT2(w2[1][20 + 4 * q + 0], bc_h2(ub[q].x), a1);
                a1 = DOT2(w2[1][20 + 4 * q + 1], bc_h2(ub[q].y), a1);
                a1 = DOT2(w2[1][20 + 4 * q + 2], bc_h2(ub[q].z), a1);
                a1 = DOT2(w2[1][20 + 4 * q + 3], bc_h2(ub[q].w), a1);
            }
        }

        y[(b * Oo + og * 2 + 0) * F2 + col] = a0;
        y[(b * Oo + og * 2 + 1) * F2 + col] = a1;
        s0 += a0; ss0 = fmaf(a0, a0, ss0);
        s1 += a1; ss1 = fmaf(a1, a1, ss1);

        // stage next batch into the other buffer
        if (bi < 15) {
#pragma unroll
            for (int k = 0; k < 5; ++k)
                if (xb[k] != -2) pat[bg][cur ^ 1][t255 + k * 256] = (_Float16)r1[k];
        }
        __syncthreads();
    }

    // reduce over the 16 f-lanes (consecutive lanes within the wave)
#pragma unroll
    for (int d = 8; d >= 1; d >>= 1) {
        s0  += __shfl_down(s0,  d, 16);
        ss0 += __shfl_down(ss0, d, 16);
        s1  += __shfl_down(s1,  d, 16);
        ss1 += __shfl_down(ss1, d, 16);
    }
    if (f == 0) {
        const int slot = blockIdx.x * 2 + bg;
        psum[(og * 2 + 0) * SLOTS + slot]   = s0;
        psumsq[(og * 2 + 0) * SLOTS + slot] = ss0;
        psum[(og * 2 + 1) * SLOTS + slot]   = s1;
        psumsq[(og * 2 + 1) * SLOTS + slot] = ss1;
    }
}

__global__ __launch_bounds__(256) void bnstats_kernel(
    const float* __restrict__ psum, const float* __restrict__ psumsq,
    const float* __restrict__ gamma, const float* __restrict__ beta,
    float* __restrict__ scsh)
{
    const int o = blockIdx.x;
    const int t = threadIdx.x;
    float s  = psum[o * SLOTS + t]   + psum[o * SLOTS + t + 256];
    float ss = psumsq[o * SLOTS + t] + psumsq[o * SLOTS + t + 256];
#pragma unroll
    for (int d = 32; d >= 1; d >>= 1) {
        s  += __shfl_down(s, d, 64);
        ss += __shfl_down(ss, d, 64);
    }
    __shared__ float ls[4], lss[4];
    int wv = t >> 6, ln = t & 63;
    if (ln == 0) { ls[wv] = s; lss[wv] = ss; }
    __syncthreads();
    if (t == 0) {
        float S   = (ls[0] + ls[1]) + (ls[2] + ls[3]);
        float SS  = (lss[0] + lss[1]) + (lss[2] + lss[3]);
        float mean = S / (float)NTOT;
        float var  = SS / (float)NTOT - mean * mean;
        float rstd = rsqrtf(var + 1e-5f);
        float scl  = gamma[o] * rstd;
        scsh[o]      = scl;
        scsh[Oo + o] = beta[o] - mean * scl;
    }
}

__global__ __launch_bounds__(256) void bnapply_kernel(
    float* __restrict__ y, const float* __restrict__ scsh)
{
    int i = blockIdx.x * 256 + threadIdx.x;    // float4 index
    float4 v = ((const float4*)y)[i];
    int o = (i >> 10) & 31;                    // F2/4 = 1024 float4 per (b,o)
    float scl = scsh[o], sh = scsh[Oo + o];
    v.x = fmaf(v.x, scl, sh);
    v.y = fmaf(v.y, scl, sh);
    v.z = fmaf(v.z, scl, sh);
    v.w = fmaf(v.w, scl, sh);
    ((float4*)y)[i] = v;
}

extern "C" void kernel_launch(void* const* d_in, const int* in_sizes, int n_in,
                              void* d_out, int out_size, void* d_ws, size_t ws_size,
                              hipStream_t stream)
{
    const float* x     = (const float*)d_in[0];
    const float* wgt   = (const float*)d_in[1];
    const float* bias  = (const float*)d_in[2];
    const float* gamma = (const float*)d_in[3];
    const float* beta  = (const float*)d_in[4];
    float* y = (float*)d_out;

    float* psum   = (float*)d_ws;               // [Oo][SLOTS]
    float* psumsq = psum + Oo * SLOTS;          // [Oo][SLOTS]
    float* scsh   = psumsq + Oo * SLOTS;        // [2][Oo]

    svconv_kernel<<<NBLKS, 512, 0, stream>>>(x, wgt, bias, y, psum, psumsq);
    bnstats_kernel<<<Oo, 256, 0, stream>>>(psum, psumsq, gamma, beta, scsh);
    bnapply_kernel<<<NTOT * Oo / 4 / 256, 256, 0, stream>>>(y, scsh);
}